// Round 11
// baseline (384.781 us; speedup 1.0000x reference)
//
#include <hip/hip_runtime.h>
#include <stdint.h>

typedef __bf16 bf16x8 __attribute__((ext_vector_type(8)));
typedef float f32x4 __attribute__((ext_vector_type(4)));
typedef unsigned short u16;
typedef unsigned int u32;

#define N_INST 50000
#define NPAD   50048   // 391 * 128
#define LIN    1024
#define D1     512
#define D2     256
#define TOPK   64
#define TDIM   49
#define NBIN   65536
#define CAND_MAX 8192
// dwords to zero: accum(520) + ids(128) + ctl(16) + hist(65536)
#define ZERO_DW (520 + 128 + 16 + NBIN)

__device__ __forceinline__ float b2f(u16 u) {
    union { float f; u32 i; } x; x.i = ((u32)u) << 16; return x.f;
}
__device__ __forceinline__ u16 f2b(float f) {
    union { float f; u32 i; } x; x.f = f;
    u32 r = x.i + 0x7FFFu + ((x.i >> 16) & 1u);   // RNE
    return (u16)(r >> 16);
}
// async global->LDS, 16B per lane. dst must be linear in lane order (wave-uniform base + lane*16).
__device__ __forceinline__ void gload16(const void* g, void* l) {
    __builtin_amdgcn_global_load_lds((const __attribute__((address_space(1))) void*)g,
                                     (__attribute__((address_space(3))) void*)l, 16, 0, 0);
}
// byte offset of a swizzled [row][64 bf16] tile element (T2 st-style XOR swizzle)
__device__ __forceinline__ u32 swz(int row, int bytecol) {
    return (u32)(row * 128 + (bytecol ^ ((row & 7) << 4)));
}

// ---------------- pack weights (tiny): W_fc -> WfcT bf16 [512][1024]; Wa/Wb -> [256][512]
// Also zeroes the accumulator/histogram region.
__global__ void pack_w(const float* __restrict__ W_fc, const float* __restrict__ Wa,
                       const float* __restrict__ Wb, u16* __restrict__ WfcT,
                       u16* __restrict__ WaT, u16* __restrict__ WbT, u32* __restrict__ zbase) {
    int gt = blockIdx.x * blockDim.x + threadIdx.x;
    int nthr = gridDim.x * blockDim.x;
    for (int z = gt; z < ZERO_DW; z += nthr) zbase[z] = 0u;
    for (int e = gt; e < D1 * LIN; e += nthr) {
        int n = e >> 10, k = e & 1023;
        WfcT[e] = f2b(W_fc[(size_t)k * D1 + n]);
    }
    for (int f = gt; f < D2 * D1; f += nthr) {
        int j = f >> 9, k = f & 511;
        WaT[f] = f2b(Wa[(size_t)k * D2 + j]);
        WbT[f] = f2b(Wb[(size_t)k * D2 + j]);
    }
}

// ---------------- GEMM1: h512 = relu(h_fp32 @ W_fc + b_fc). m97 occupancy regime:
// 256 threads (4 waves 2x2, wave tile 64x64), 128x128 tile, BK=64, LDS 32 KB
// -> 4 blocks/CU co-resident: cross-block overlap hides the barrier drain (m114).
// A: coalesced fp32 chunk loads (16 lanes/row) -> cvt bf16 -> swizzled ds_write,
// staged in two 4-chunk rounds to keep VGPR under the 4-wave cap (R9 spill lesson).
// B: global_load_lds with pre-swizzled source. All LDS reads XOR-swizzled (T2).
__global__ __launch_bounds__(256, 4)
void gemm_fc(const float* __restrict__ h, const u16* __restrict__ WfcT,
             const float* __restrict__ b_fc, u16* __restrict__ h512) {
    __shared__ __align__(16) u16 lA[128 * 64];    // 16 KB
    __shared__ __align__(16) u16 lB[128 * 64];    // 16 KB
    const int tid = threadIdx.x;
    const int lane = tid & 63, wid = tid >> 6;
    const int wr = wid >> 1, wc = wid & 1;        // 2 x 2 wave grid, 64x64 each
    const int lanelo = lane & 15, lanehi = lane >> 4;
    const int row0 = blockIdx.y * 128;
    const int col0 = blockIdx.x * 128;

    f32x4 acc[4][4];
    const f32x4 z4 = {0.f, 0.f, 0.f, 0.f};
    #pragma unroll
    for (int m = 0; m < 4; ++m)
        #pragma unroll
        for (int n = 0; n < 4; ++n) acc[m][n] = z4;

    for (int kt = 0; kt < LIN / 64; ++kt) {
        // B: 128x64 bf16 = 1024 chunks, 4/thread, async direct-to-LDS (source pre-swizzled)
        #pragma unroll
        for (int q = 0; q < 4; ++q) {
            int c = tid + 256 * q;
            int col = c >> 3, d8 = c & 7;
            int k8 = d8 ^ (col & 7);
            gload16(WfcT + (size_t)(col0 + col) * LIN + kt * 64 + k8 * 8, (char*)lB + c * 16);
        }
        // A: 128 rows x 16 float4-chunks = 2048 chunks, 8/thread in two rounds of 4.
        // Chunk order: 16 consecutive tids cover one row -> wave spans 4 rows, coalesced.
        #pragma unroll
        for (int half = 0; half < 2; ++half) {
            float4 av[4];
            #pragma unroll
            for (int q = 0; q < 4; ++q) {
                int c = tid + 256 * (half * 4 + q);
                int row = c >> 4, k4 = c & 15;
                int srow = row0 + row; if (srow >= N_INST) srow = N_INST - 1;
                av[q] = *(const float4*)(h + (size_t)srow * LIN + kt * 64 + k4 * 4);
            }
            #pragma unroll
            for (int q = 0; q < 4; ++q) {
                int c = tid + 256 * (half * 4 + q);
                int row = c >> 4, k4 = c & 15;
                ushort4 w;
                w.x = f2b(av[q].x); w.y = f2b(av[q].y); w.z = f2b(av[q].z); w.w = f2b(av[q].w);
                *(ushort4*)((char*)lA + swz(row, k4 * 8)) = w;
            }
        }
        __syncthreads();
        #pragma unroll
        for (int kk = 0; kk < 2; ++kk) {
            bf16x8 af[4], bfr[4];
            #pragma unroll
            for (int m = 0; m < 4; ++m) {
                int row = wr * 64 + m * 16 + lanelo;
                af[m] = *(const bf16x8*)((char*)lA + swz(row, kk * 64 + lanehi * 16));
            }
            #pragma unroll
            for (int n = 0; n < 4; ++n) {
                int col = wc * 64 + n * 16 + lanelo;
                bfr[n] = *(const bf16x8*)((char*)lB + swz(col, kk * 64 + lanehi * 16));
            }
            #pragma unroll
            for (int m = 0; m < 4; ++m)
                #pragma unroll
                for (int n = 0; n < 4; ++n)
                    acc[m][n] = __builtin_amdgcn_mfma_f32_16x16x32_bf16(af[m], bfr[n], acc[m][n], 0, 0, 0);
        }
        __syncthreads();
    }
    // epilogue: bias + relu -> bf16
    #pragma unroll
    for (int n = 0; n < 4; ++n) {
        int col = col0 + wc * 64 + n * 16 + lanelo;
        float bias = b_fc[col];
        #pragma unroll
        for (int m = 0; m < 4; ++m) {
            int rbase = row0 + wr * 64 + m * 16 + 4 * lanehi;
            #pragma unroll
            for (int r = 0; r < 4; ++r) {
                float v = acc[m][n][r] + bias;
                v = v > 0.f ? v : 0.f;
                h512[(size_t)(rbase + r) * D1 + col] = f2b(v);
            }
        }
    }
}

// ---------------- GEMM2 fused + sortable keys + 64K-bin key histogram + Z/M partials
// (exact R6 version — the 308.7 us measurement)
__global__ __launch_bounds__(512, 2)
void gemm_attn(const u16* __restrict__ h512, const u16* __restrict__ WaT,
               const u16* __restrict__ WbT, const float* __restrict__ ba,
               const float* __restrict__ bb, const float* __restrict__ Wc,
               const float* __restrict__ bc, float* __restrict__ araw,
               u32* __restrict__ uarr, u32* __restrict__ hist,
               float* __restrict__ Zacc, float* __restrict__ Mpart) {
    __shared__ __align__(16) u16 lA[128 * 64];
    __shared__ __align__(16) u16 lBa[256 * 64];
    __shared__ __align__(16) u16 lBb[256 * 64];
    __shared__ float rsum[128];
    __shared__ float sW[128];
    const int tid = threadIdx.x;
    const int lane = tid & 63, wid = tid >> 6;
    const int wr = wid >> 2, wc4 = wid & 3;
    const int lanelo = lane & 15, lanehi = lane >> 4;
    const int row0 = blockIdx.x * 128;

    f32x4 accA[4][4], accB[4][4];
    const f32x4 z4 = {0.f, 0.f, 0.f, 0.f};
    for (int m = 0; m < 4; ++m)
        for (int n = 0; n < 4; ++n) { accA[m][n] = z4; accB[m][n] = z4; }

    for (int kt = 0; kt < D1 / 64; ++kt) {
        #pragma unroll
        for (int q = 0; q < 2; ++q) {
            int c = tid + 512 * q;
            int row = c >> 3, d8 = c & 7;
            int k8 = d8 ^ (row & 7);
            gload16(h512 + (size_t)(row0 + row) * D1 + kt * 64 + k8 * 8, (char*)lA + c * 16);
        }
        #pragma unroll
        for (int q = 0; q < 4; ++q) {
            int c = tid + 512 * q;
            int col = c >> 3, d8 = c & 7;
            int k8 = d8 ^ (col & 7);
            gload16(WaT + (size_t)col * D1 + kt * 64 + k8 * 8, (char*)lBa + c * 16);
            gload16(WbT + (size_t)col * D1 + kt * 64 + k8 * 8, (char*)lBb + c * 16);
        }
        __syncthreads();
        #pragma unroll
        for (int kk = 0; kk < 2; ++kk) {
            bf16x8 af[4], ga[4], gb[4];
            #pragma unroll
            for (int m = 0; m < 4; ++m) {
                int row = wr * 64 + m * 16 + lanelo;
                af[m] = *(const bf16x8*)((char*)lA + swz(row, kk * 64 + lanehi * 16));
            }
            #pragma unroll
            for (int n = 0; n < 4; ++n) {
                int col = wc4 * 64 + n * 16 + lanelo;
                u32 off = swz(col, kk * 64 + lanehi * 16);
                ga[n] = *(const bf16x8*)((char*)lBa + off);
                gb[n] = *(const bf16x8*)((char*)lBb + off);
            }
            #pragma unroll
            for (int m = 0; m < 4; ++m)
                #pragma unroll
                for (int n = 0; n < 4; ++n) {
                    accA[m][n] = __builtin_amdgcn_mfma_f32_16x16x32_bf16(af[m], ga[n], accA[m][n], 0, 0, 0);
                    accB[m][n] = __builtin_amdgcn_mfma_f32_16x16x32_bf16(af[m], gb[n], accB[m][n], 0, 0, 0);
                }
        }
        __syncthreads();
    }

    if (tid < 128) rsum[tid] = 0.f;
    __syncthreads();

    float baR[4], bbR[4], wcR[4];
    #pragma unroll
    for (int n = 0; n < 4; ++n) {
        int j = wc4 * 64 + n * 16 + lanelo;
        baR[n] = ba[j]; bbR[n] = bb[j]; wcR[n] = Wc[j];
    }
    #pragma unroll
    for (int m = 0; m < 4; ++m) {
        #pragma unroll
        for (int r = 0; r < 4; ++r) {
            float s = 0.f;
            #pragma unroll
            for (int n = 0; n < 4; ++n) {
                float av = accA[m][n][r] + baR[n];
                float bv = accB[m][n][r] + bbR[n];
                float p = tanhf(av) / (1.f + expf(-bv));
                s += p * wcR[n];
            }
            s += __shfl_xor(s, 1); s += __shfl_xor(s, 2);
            s += __shfl_xor(s, 4); s += __shfl_xor(s, 8);
            if (lanelo == 0) atomicAdd(&rsum[wr * 64 + m * 16 + 4 * lanehi + r], s);
        }
    }
    __syncthreads();

    if (tid < 128) {
        int rg = row0 + tid;
        float e = 0.f;
        if (rg < N_INST) {
            float a = rsum[tid] + bc[0];
            araw[rg] = a;
            u32 bits = __float_as_uint(a);
            u32 key = (bits & 0x80000000u) ? ~bits : (bits | 0x80000000u);
            uarr[rg] = key;
            atomicAdd(&hist[key >> 16], 1u);
            e = expf(a);
        }
        sW[tid] = e;
    }
    __syncthreads();
    if (tid < 128) {
        float e = sW[tid];
        for (int o = 32; o > 0; o >>= 1) e += __shfl_xor(e, o);
        if (lane == 0) atomicAdd(Zacc, e);
    }
    float accM = 0.f;
    for (int i = 0; i < 128; ++i)
        accM += sW[i] * b2f(h512[(size_t)(row0 + i) * D1 + tid]);
    atomicAdd(&Mpart[tid], accM);
}

// ---------------- topk collect with inline hist scan (every block computes boundaries)
__global__ void topk_collect(const u32* __restrict__ hist, const u32* __restrict__ uarr,
                             int* __restrict__ ctl, int* __restrict__ ids,
                             u32* __restrict__ cV0, int* __restrict__ cI0,
                             u32* __restrict__ cV1, int* __restrict__ cI1) {
    __shared__ int part[256];
    __shared__ int sp0, sb0, sp1, sb1;
    const int t = threadIdx.x;                 // 256
    const uint4* h4 = (const uint4*)hist;
    int s = 0;
    for (int j = 0; j < 64; ++j) {
        uint4 v = h4[t * 64 + j];
        s += (int)(v.x + v.y + v.z + v.w);
    }
    part[t] = s;
    __syncthreads();
    for (int off = 1; off < 256; off <<= 1) {
        int v = part[t];
        int a = (t >= off) ? part[t - off] : 0;
        __syncthreads();
        part[t] = v + a;
        __syncthreads();
    }
    int run = part[t] - s;
    for (int j = 0; j < 64; ++j) {
        uint4 v = h4[t * 64 + j];
        int c4[4]; c4[0] = (int)v.x; c4[1] = (int)v.y; c4[2] = (int)v.z; c4[3] = (int)v.w;
        #pragma unroll
        for (int e = 0; e < 4; ++e) {
            int cnt = c4[e];
            if (cnt > 0) {
                int b = t * 256 + j * 4 + e;
                int less = run, greater = N_INST - run - cnt;
                if (greater < TOPK && greater + cnt >= TOPK) { sp0 = b; sb0 = greater; }
                if (less < TOPK && less + cnt >= TOPK)       { sp1 = b; sb1 = less; }
            }
            run += cnt;
        }
    }
    __syncthreads();
    const int p0 = sp0, p1 = sp1;
    if (blockIdx.x == 0 && t == 0) { ctl[0] = sp0; ctl[1] = sb0; ctl[2] = sp1; ctl[3] = sb1; }

    int gt = blockIdx.x * blockDim.x + t;
    int nthr = gridDim.x * blockDim.x;
    for (int i = gt; i < N_INST; i += nthr) {
        u32 v = uarr[i];
        int b = (int)(v >> 16);
        if (b > p0)       { int p = atomicAdd(&ctl[8], 1);  ids[p] = i; }
        else if (b == p0) { int p = atomicAdd(&ctl[9], 1);  if (p < CAND_MAX) { cV0[p] = v; cI0[p] = i; } }
        if (b < p1)       { int p = atomicAdd(&ctl[10], 1); ids[TOPK + p] = i; }
        else if (b == p1) { int p = atomicAdd(&ctl[11], 1); if (p < CAND_MAX) { cV1[p] = v; cI1[p] = i; } }
    }
}

// ---------------- tail: topk finish + instance CE loss + final head (one block, 256 thr)
__global__ void tail_fused(const int* __restrict__ ctl,
                           const u32* __restrict__ cV0, const int* __restrict__ cI0,
                           const u32* __restrict__ cV1, const int* __restrict__ cI1,
                           int* __restrict__ ids, const u16* __restrict__ h512,
                           const float* __restrict__ W_inst, const float* __restrict__ b_inst,
                           const int* __restrict__ label, const float* __restrict__ Mpart,
                           const float* __restrict__ Zacc, const float* __restrict__ tabular,
                           const float* __restrict__ W_img, const float* __restrict__ b_img,
                           const float* __restrict__ W_tab, const float* __restrict__ b_tab,
                           const float* __restrict__ W_cls, const float* __restrict__ b_cls,
                           float* __restrict__ d_out) {
    __shared__ int h8[256];
    __shared__ int eq[2048];
    __shared__ int s_d1, s_k1, s_d2, s_fill, s_eqc;
    __shared__ float lsum;
    __shared__ float sM[512];
    __shared__ float stab[TDIM];
    __shared__ float red0[256], red1[256];
    __shared__ float simg;
    const int tid = threadIdx.x;               // 256
    const int lane = tid & 63, wid = tid >> 6;

    for (int mode = 0; mode < 2; ++mode) {
        int basem = ctl[mode * 2 + 1];
        int need = TOPK - basem;
        int ccnt = ctl[9 + mode * 2];
        if (ccnt > CAND_MAX) ccnt = CAND_MAX;
        const u32* cV = mode ? cV1 : cV0;
        const int* cI = mode ? cI1 : cI0;
        int* dst = ids + mode * TOPK;
        h8[tid] = 0; __syncthreads();
        for (int i = tid; i < ccnt; i += 256) atomicAdd(&h8[(cV[i] >> 8) & 255u], 1);
        __syncthreads();
        if (tid == 0) {
            int acc = 0, d, k = need;
            if (mode == 0) { for (d = 255; d >= 0; --d) { acc += h8[d]; if (acc >= k) break; } }
            else           { for (d = 0; d < 256; ++d)  { acc += h8[d]; if (acc >= k) break; } }
            s_d1 = d; s_k1 = k - (acc - h8[d]);
        }
        __syncthreads();
        int d1 = s_d1, k1 = s_k1;
        h8[tid] = 0; __syncthreads();
        for (int i = tid; i < ccnt; i += 256) {
            u32 v = cV[i];
            if (((v >> 8) & 255u) == (u32)d1) atomicAdd(&h8[v & 255u], 1);
        }
        __syncthreads();
        if (tid == 0) {
            int acc = 0, d, k = k1;
            if (mode == 0) { for (d = 255; d >= 0; --d) { acc += h8[d]; if (acc >= k) break; } }
            else           { for (d = 0; d < 256; ++d)  { acc += h8[d]; if (acc >= k) break; } }
            s_d2 = d; s_fill = 0; s_eqc = 0;
        }
        __syncthreads();
        u32 vth = ((u32)ctl[mode * 2] << 16) | ((u32)d1 << 8) | (u32)s_d2;
        for (int i = tid; i < ccnt; i += 256) {
            u32 v = cV[i];
            bool better = mode == 0 ? (v > vth) : (v < vth);
            if (better)        { int p = atomicAdd(&s_fill, 1); dst[basem + p] = cI[i]; }
            else if (v == vth) { int p = atomicAdd(&s_eqc, 1);  if (p < 2048) eq[p] = cI[i]; }
        }
        __syncthreads();
        if (tid == 0) {
            int have = basem + s_fill;
            int rem = TOPK - have;
            int m = s_eqc < 2048 ? s_eqc : 2048;
            int last = -1;
            for (int q = 0; q < rem; ++q) {
                int best = 0x7FFFFFFF;
                for (int s = 0; s < m; ++s) { int ix = eq[s]; if (ix > last && ix < best) best = ix; }
                dst[have + q] = best; last = best;
            }
        }
        __syncthreads();
    }

    if (tid == 0) lsum = 0.f;
    __syncthreads();
    const int lab = label[0];
    const float* W = W_inst + (size_t)lab * (D1 * 2);
    const float b0 = b_inst[lab * 2 + 0], b1 = b_inst[lab * 2 + 1];
    for (int i = 0; i < 32; ++i) {
        int r = wid * 32 + i;
        int row = ids[r];
        float s0 = 0.f, s1 = 0.f;
        for (int s = 0; s < 8; ++s) {
            int j = lane + 64 * s;
            float hv = b2f(h512[(size_t)row * D1 + j]);
            s0 += hv * W[j * 2 + 0];
            s1 += hv * W[j * 2 + 1];
        }
        for (int o = 32; o > 0; o >>= 1) { s0 += __shfl_xor(s0, o); s1 += __shfl_xor(s1, o); }
        if (lane == 0) {
            float l0 = s0 + b0, l1 = s1 + b1;
            float mx = fmaxf(l0, l1);
            float lse = mx + logf(expf(l0 - mx) + expf(l1 - mx));
            float lt = (r < TOPK) ? l1 : l0;
            atomicAdd(&lsum, lse - lt);
        }
    }
    __syncthreads();
    if (tid == 0) d_out[50005] = lsum / 128.f;

    float invZ = 1.f / Zacc[0];
    sM[tid] = Mpart[tid] * invZ;
    sM[tid + 256] = Mpart[tid + 256] * invZ;
    red0[tid] = sM[tid] * W_img[tid] + sM[tid + 256] * W_img[tid + 256];
    __syncthreads();
    for (int o = 128; o > 0; o >>= 1) { if (tid < o) red0[tid] += red0[tid + o]; __syncthreads(); }
    if (tid == 0) simg = 1.f / (1.f + expf(-(red0[0] + b_img[0])));
    if (tid < TDIM) {
        float t = b_tab[tid];
        for (int kx = 0; kx < TDIM; ++kx) t += tabular[kx] * W_tab[kx * TDIM + tid];
        stab[tid] = t;
    }
    __syncthreads();
    if (tid == 0) {
        float mx = stab[0];
        for (int o = 1; o < TDIM; ++o) mx = fmaxf(mx, stab[o]);
        float ss = 0.f;
        for (int o = 0; o < TDIM; ++o) { float e = expf(stab[o] - mx); stab[o] = e; ss += e; }
        for (int o = 0; o < TDIM; ++o) stab[o] = (stab[o] / ss) * tabular[o];
    }
    __syncthreads();
    float img = simg;
    float a0 = 0.f, a1 = 0.f;
    for (int j = tid; j < D1 + TDIM; j += 256) {
        float w = (j < D1) ? img * sM[j] : stab[j - D1];
        a0 += w * W_cls[j * 2 + 0];
        a1 += w * W_cls[j * 2 + 1];
    }
    red0[tid] = a0; red1[tid] = a1;
    __syncthreads();
    for (int o = 128; o > 0; o >>= 1) {
        if (tid < o) { red0[tid] += red0[tid + o]; red1[tid] += red1[tid + o]; }
        __syncthreads();
    }
    if (tid == 0) {
        float l0 = red0[0] + b_cls[0];
        float l1 = red1[0] + b_cls[1];
        d_out[0] = l0; d_out[1] = l1;
        float mx = fmaxf(l0, l1);
        float e0 = expf(l0 - mx), e1 = expf(l1 - mx);
        d_out[2] = e0 / (e0 + e1);
        d_out[3] = e1 / (e0 + e1);
        d_out[4] = (l1 > l0) ? 1.f : 0.f;
    }
}

extern "C" void kernel_launch(void* const* d_in, const int* in_sizes, int n_in,
                              void* d_out, int out_size, void* d_ws, size_t ws_size,
                              hipStream_t stream) {
    const float* h       = (const float*)d_in[0];
    const float* tabular = (const float*)d_in[1];
    const int*   label   = (const int*)d_in[2];
    const float* W_fc    = (const float*)d_in[3];
    const float* b_fc    = (const float*)d_in[4];
    const float* Wa      = (const float*)d_in[5];
    const float* ba      = (const float*)d_in[6];
    const float* Wb      = (const float*)d_in[7];
    const float* bb      = (const float*)d_in[8];
    const float* Wc      = (const float*)d_in[9];
    const float* bc      = (const float*)d_in[10];
    const float* W_inst  = (const float*)d_in[11];
    const float* b_inst  = (const float*)d_in[12];
    const float* W_img   = (const float*)d_in[13];
    const float* b_img   = (const float*)d_in[14];
    const float* W_tab   = (const float*)d_in[15];
    const float* b_tab   = (const float*)d_in[16];
    const float* W_cls   = (const float*)d_in[17];
    const float* b_cls   = (const float*)d_in[18];
    float* out = (float*)d_out;

    // workspace layout (~53 MB)
    u16* h512 = (u16*)d_ws;                          // NPAD x 512 bf16      (51.2 MB)
    u16* WfcT = h512 + (size_t)NPAD * D1;            // 512 x 1024 bf16      (1 MB)
    u16* WaT  = WfcT + (size_t)D1 * LIN;             // 256 x 512 bf16
    u16* WbT  = WaT + (size_t)D2 * D1;
    u32* uarr = (u32*)(WbT + (size_t)D2 * D1);       // NPAD sortable keys
    float* accum = (float*)(uarr + NPAD);            // [0]=Z, [8..520)=Mpart
    float* Zacc  = accum;
    float* Mpart = accum + 8;
    int* ids = (int*)(accum + 8 + D1);               // 128 selected indices
    int* ctl = ids + 128;                            // 16 ints: buckets+counters
    u32* hist = (u32*)(ctl + 16);                    // 65536 bins
    u32* cV0 = hist + NBIN;
    int* cI0 = (int*)(cV0 + CAND_MAX);
    u32* cV1 = (u32*)(cI0 + CAND_MAX);
    int* cI1 = (int*)(cV1 + CAND_MAX);

    pack_w<<<dim3(256), dim3(256), 0, stream>>>(W_fc, Wa, Wb, WfcT, WaT, WbT, (u32*)accum);
    gemm_fc<<<dim3(4, NPAD / 128), dim3(256), 0, stream>>>(h, WfcT, b_fc, h512);
    gemm_attn<<<dim3(NPAD / 128), dim3(512), 0, stream>>>(
        h512, WaT, WbT, ba, bb, Wc, bc, out + 5, uarr, hist, Zacc, Mpart);
    topk_collect<<<dim3(128), dim3(256), 0, stream>>>(hist, uarr, ctl, ids, cV0, cI0, cV1, cI1);
    tail_fused<<<dim3(1), dim3(256), 0, stream>>>(
        ctl, cV0, cI0, cV1, cI1, ids, h512, W_inst, b_inst, label,
        Mpart, Zacc, tabular, W_img, b_img, W_tab, b_tab, W_cls, b_cls, out);
}

// Round 12
// 297.483 us; speedup vs baseline: 1.2935x; 1.2935x over previous
//
#include <hip/hip_runtime.h>
#include <stdint.h>

typedef __bf16 bf16x8 __attribute__((ext_vector_type(8)));
typedef float f32x4 __attribute__((ext_vector_type(4)));
typedef unsigned short u16;
typedef unsigned int u32;

#define N_INST 50000
#define NPAD   50048   // 391 * 128
#define LIN    1024
#define D1     512
#define D2     256
#define TOPK   64
#define TDIM   49
#define NBIN   65536
#define CAND_MAX 8192
// dwords to zero: accum(520) + ids(128) + ctl(16) + hist(65536)
#define ZERO_DW (520 + 128 + 16 + NBIN)

__device__ __forceinline__ float b2f(u16 u) {
    union { float f; u32 i; } x; x.i = ((u32)u) << 16; return x.f;
}
__device__ __forceinline__ u16 f2b(float f) {
    union { float f; u32 i; } x; x.f = f;
    u32 r = x.i + 0x7FFFu + ((x.i >> 16) & 1u);   // RNE
    return (u16)(r >> 16);
}
// async global->LDS, 16B per lane. dst must be linear in lane order (wave-uniform base + lane*16).
__device__ __forceinline__ void gload16(const void* g, void* l) {
    __builtin_amdgcn_global_load_lds((const __attribute__((address_space(1))) void*)g,
                                     (__attribute__((address_space(3))) void*)l, 16, 0, 0);
}
// byte offset of a swizzled [row][64 bf16] tile element (T2 st-style XOR swizzle)
__device__ __forceinline__ u32 swz(int row, int bytecol) {
    return (u32)(row * 128 + (bytecol ^ ((row & 7) << 4)));
}

// ---------------- pack weights (tiny): W_fc -> WfcT bf16 [512][1024]; Wa/Wb -> [256][512]
// Also zeroes the accumulator/histogram region.
__global__ void pack_w(const float* __restrict__ W_fc, const float* __restrict__ Wa,
                       const float* __restrict__ Wb, u16* __restrict__ WfcT,
                       u16* __restrict__ WaT, u16* __restrict__ WbT, u32* __restrict__ zbase) {
    int gt = blockIdx.x * blockDim.x + threadIdx.x;
    int nthr = gridDim.x * blockDim.x;
    for (int z = gt; z < ZERO_DW; z += nthr) zbase[z] = 0u;
    for (int e = gt; e < D1 * LIN; e += nthr) {
        int n = e >> 10, k = e & 1023;
        WfcT[e] = f2b(W_fc[(size_t)k * D1 + n]);
    }
    for (int f = gt; f < D2 * D1; f += nthr) {
        int j = f >> 9, k = f & 511;
        WaT[f] = f2b(Wa[(size_t)k * D2 + j]);
        WbT[f] = f2b(Wb[(size_t)k * D2 + j]);
    }
}

// ---------------- GEMM1: h512 = relu(h_fp32 @ W_fc + b_fc). Counted-vmcnt pipeline (T4):
// raw s_barrier (NO vmcnt(0) drain) + explicit s_waitcnt vmcnt(4) so B gloads and A reg-loads
// stay in flight across the barrier for a full MFMA section. R10 proved __syncthreads'
// vmcnt(0) drain defeats double-buffering; this is the documented fix (§5.5 T3/T4).
// Cross-wave LDS safety: each wave's vmcnt covering its own gloads precedes the barrier
// that precedes any read (two-barrier rule). BM=128, BN=256, BK=64, 8 waves, LDS 96 KB.
__global__ __launch_bounds__(512, 2)
void gemm_fc(const float* __restrict__ h, const u16* __restrict__ WfcT,
             const float* __restrict__ b_fc, u16* __restrict__ h512) {
    __shared__ __align__(16) u16 lA[2][128 * 64];   // 2 x 16 KB
    __shared__ __align__(16) u16 lB[2][256 * 64];   // 2 x 32 KB
    const int tid = threadIdx.x;
    const int lane = tid & 63, wid = tid >> 6;
    const int wr = wid >> 2, wc = wid & 3;          // 2 x 4 wave grid, 64x64 each
    const int lanelo = lane & 15, lanehi = lane >> 4;
    const int row0 = blockIdx.y * 128;
    const int col0 = blockIdx.x * 256;
    const int NT = LIN / 64;                        // 16 K-steps

    const int arow = tid >> 2;                      // 0..127
    const int aseg = tid & 3;                       // 16 floats each
    int srow = row0 + arow; if (srow >= N_INST) srow = N_INST - 1;
    const float* abase = h + (size_t)srow * LIN + aseg * 16;
    const u32 awo0 = swz(arow, aseg * 32);
    const u32 awo1 = swz(arow, aseg * 32 + 16);

    f32x4 acc[4][4];
    const f32x4 z4 = {0.f, 0.f, 0.f, 0.f};
    #pragma unroll
    for (int m = 0; m < 4; ++m)
        #pragma unroll
        for (int n = 0; n < 4; ++n) acc[m][n] = z4;

    float4 a0, a1, a2, a3;                          // in-flight A regs

    #define LOAD_A(kt_)                                                     \
        do {                                                                \
            const float4* ap_ = (const float4*)(abase + (kt_) * 64);        \
            a0 = ap_[0]; a1 = ap_[1]; a2 = ap_[2]; a3 = ap_[3];             \
        } while (0)

    #define STAGE_B(buf_, kt_)                                                           \
        do {                                                                             \
            _Pragma("unroll")                                                            \
            for (int q_ = 0; q_ < 4; ++q_) {                                             \
                int c_ = tid + 512 * q_;                                                 \
                int col_ = c_ >> 3, d8_ = c_ & 7;                                        \
                int k8_ = d8_ ^ (col_ & 7);                                              \
                gload16(WfcT + (size_t)(col0 + col_) * LIN + (kt_) * 64 + k8_ * 8,       \
                        (char*)lB[buf_] + c_ * 16);                                      \
            }                                                                            \
        } while (0)

    #define WRITE_A(buf_)                                                                \
        do {                                                                             \
            bf16x8 w0_, w1_;                                                             \
            w0_[0] = (__bf16)a0.x; w0_[1] = (__bf16)a0.y; w0_[2] = (__bf16)a0.z; w0_[3] = (__bf16)a0.w; \
            w0_[4] = (__bf16)a1.x; w0_[5] = (__bf16)a1.y; w0_[6] = (__bf16)a1.z; w0_[7] = (__bf16)a1.w; \
            w1_[0] = (__bf16)a2.x; w1_[1] = (__bf16)a2.y; w1_[2] = (__bf16)a2.z; w1_[3] = (__bf16)a2.w; \
            w1_[4] = (__bf16)a3.x; w1_[5] = (__bf16)a3.y; w1_[6] = (__bf16)a3.z; w1_[7] = (__bf16)a3.w; \
            *(bf16x8*)((char*)lA[buf_] + awo0) = w0_;                                    \
            *(bf16x8*)((char*)lA[buf_] + awo1) = w1_;                                    \
        } while (0)

    // prologue: A0 regs, B0 gloads; write A0; A1 regs; drain B0; barrier.
    LOAD_A(0);                                      // A0(4)
    STAGE_B(0, 0);                                  // +B0(4)
    asm volatile("s_waitcnt vmcnt(4)" ::: "memory");    // A0 regs done (oldest 4)
    __builtin_amdgcn_sched_barrier(0);
    WRITE_A(0);
    LOAD_A(1);                                      // outstanding: B0(4), A1(4)
    asm volatile("s_waitcnt vmcnt(4)" ::: "memory");    // B0 landed; A1 rides
    asm volatile("s_waitcnt lgkmcnt(0)" ::: "memory");
    __builtin_amdgcn_sched_barrier(0);
    __builtin_amdgcn_s_barrier();

    for (int kt = 0; kt < NT; ++kt) {
        const int cur = kt & 1, nxt = cur ^ 1;
        // entering: lA[cur]/lB[cur] valid+visible; outstanding: A(kt+1)(4) [if exists]
        if (kt + 1 < NT) STAGE_B(nxt, kt + 1);      // +B(kt+1): in flight through MFMA
        __builtin_amdgcn_sched_barrier(0);
        #pragma unroll
        for (int kk = 0; kk < 2; ++kk) {
            bf16x8 af[4], bfr[4];
            #pragma unroll
            for (int m = 0; m < 4; ++m) {
                int row = wr * 64 + m * 16 + lanelo;
                af[m] = *(const bf16x8*)((char*)lA[cur] + swz(row, kk * 64 + lanehi * 16));
            }
            #pragma unroll
            for (int n = 0; n < 4; ++n) {
                int col = wc * 64 + n * 16 + lanelo;
                bfr[n] = *(const bf16x8*)((char*)lB[cur] + swz(col, kk * 64 + lanehi * 16));
            }
            #pragma unroll
            for (int m = 0; m < 4; ++m)
                #pragma unroll
                for (int n = 0; n < 4; ++n)
                    acc[m][n] = __builtin_amdgcn_mfma_f32_16x16x32_bf16(af[m], bfr[n], acc[m][n], 0, 0, 0);
        }
        if (kt + 1 < NT) {
            asm volatile("s_waitcnt vmcnt(4)" ::: "memory");   // A(kt+1) regs done (older than B(kt+1))
            __builtin_amdgcn_sched_barrier(0);
            WRITE_A(nxt);
            if (kt + 2 < NT) {
                LOAD_A(kt + 2);                                // outstanding: B(kt+1)(4), A(kt+2)(4)
                asm volatile("s_waitcnt vmcnt(4)" ::: "memory"); // B(kt+1) landed; A(kt+2) rides barrier
            } else {
                asm volatile("s_waitcnt vmcnt(0)" ::: "memory"); // B(kt+1) landed
            }
            asm volatile("s_waitcnt lgkmcnt(0)" ::: "memory");   // ds_writes visible
            __builtin_amdgcn_sched_barrier(0);
            __builtin_amdgcn_s_barrier();
        }
    }
    #undef LOAD_A
    #undef STAGE_B
    #undef WRITE_A

    // epilogue: bias + relu -> bf16
    #pragma unroll
    for (int n = 0; n < 4; ++n) {
        int col = col0 + wc * 64 + n * 16 + lanelo;
        float bias = b_fc[col];
        #pragma unroll
        for (int m = 0; m < 4; ++m) {
            int rbase = row0 + wr * 64 + m * 16 + 4 * lanehi;
            #pragma unroll
            for (int r = 0; r < 4; ++r) {
                float v = acc[m][n][r] + bias;
                v = v > 0.f ? v : 0.f;
                h512[(size_t)(rbase + r) * D1 + col] = f2b(v);
            }
        }
    }
}

// ---------------- GEMM2 fused + sortable keys + 64K-bin key histogram + Z/M partials
// (exact R6 version — the 308.7 us measurement)
__global__ __launch_bounds__(512, 2)
void gemm_attn(const u16* __restrict__ h512, const u16* __restrict__ WaT,
               const u16* __restrict__ WbT, const float* __restrict__ ba,
               const float* __restrict__ bb, const float* __restrict__ Wc,
               const float* __restrict__ bc, float* __restrict__ araw,
               u32* __restrict__ uarr, u32* __restrict__ hist,
               float* __restrict__ Zacc, float* __restrict__ Mpart) {
    __shared__ __align__(16) u16 lA[128 * 64];
    __shared__ __align__(16) u16 lBa[256 * 64];
    __shared__ __align__(16) u16 lBb[256 * 64];
    __shared__ float rsum[128];
    __shared__ float sW[128];
    const int tid = threadIdx.x;
    const int lane = tid & 63, wid = tid >> 6;
    const int wr = wid >> 2, wc4 = wid & 3;
    const int lanelo = lane & 15, lanehi = lane >> 4;
    const int row0 = blockIdx.x * 128;

    f32x4 accA[4][4], accB[4][4];
    const f32x4 z4 = {0.f, 0.f, 0.f, 0.f};
    for (int m = 0; m < 4; ++m)
        for (int n = 0; n < 4; ++n) { accA[m][n] = z4; accB[m][n] = z4; }

    for (int kt = 0; kt < D1 / 64; ++kt) {
        #pragma unroll
        for (int q = 0; q < 2; ++q) {
            int c = tid + 512 * q;
            int row = c >> 3, d8 = c & 7;
            int k8 = d8 ^ (row & 7);
            gload16(h512 + (size_t)(row0 + row) * D1 + kt * 64 + k8 * 8, (char*)lA + c * 16);
        }
        #pragma unroll
        for (int q = 0; q < 4; ++q) {
            int c = tid + 512 * q;
            int col = c >> 3, d8 = c & 7;
            int k8 = d8 ^ (col & 7);
            gload16(WaT + (size_t)col * D1 + kt * 64 + k8 * 8, (char*)lBa + c * 16);
            gload16(WbT + (size_t)col * D1 + kt * 64 + k8 * 8, (char*)lBb + c * 16);
        }
        __syncthreads();
        #pragma unroll
        for (int kk = 0; kk < 2; ++kk) {
            bf16x8 af[4], ga[4], gb[4];
            #pragma unroll
            for (int m = 0; m < 4; ++m) {
                int row = wr * 64 + m * 16 + lanelo;
                af[m] = *(const bf16x8*)((char*)lA + swz(row, kk * 64 + lanehi * 16));
            }
            #pragma unroll
            for (int n = 0; n < 4; ++n) {
                int col = wc4 * 64 + n * 16 + lanelo;
                u32 off = swz(col, kk * 64 + lanehi * 16);
                ga[n] = *(const bf16x8*)((char*)lBa + off);
                gb[n] = *(const bf16x8*)((char*)lBb + off);
            }
            #pragma unroll
            for (int m = 0; m < 4; ++m)
                #pragma unroll
                for (int n = 0; n < 4; ++n) {
                    accA[m][n] = __builtin_amdgcn_mfma_f32_16x16x32_bf16(af[m], ga[n], accA[m][n], 0, 0, 0);
                    accB[m][n] = __builtin_amdgcn_mfma_f32_16x16x32_bf16(af[m], gb[n], accB[m][n], 0, 0, 0);
                }
        }
        __syncthreads();
    }

    if (tid < 128) rsum[tid] = 0.f;
    __syncthreads();

    float baR[4], bbR[4], wcR[4];
    #pragma unroll
    for (int n = 0; n < 4; ++n) {
        int j = wc4 * 64 + n * 16 + lanelo;
        baR[n] = ba[j]; bbR[n] = bb[j]; wcR[n] = Wc[j];
    }
    #pragma unroll
    for (int m = 0; m < 4; ++m) {
        #pragma unroll
        for (int r = 0; r < 4; ++r) {
            float s = 0.f;
            #pragma unroll
            for (int n = 0; n < 4; ++n) {
                float av = accA[m][n][r] + baR[n];
                float bv = accB[m][n][r] + bbR[n];
                float p = tanhf(av) / (1.f + expf(-bv));
                s += p * wcR[n];
            }
            s += __shfl_xor(s, 1); s += __shfl_xor(s, 2);
            s += __shfl_xor(s, 4); s += __shfl_xor(s, 8);
            if (lanelo == 0) atomicAdd(&rsum[wr * 64 + m * 16 + 4 * lanehi + r], s);
        }
    }
    __syncthreads();

    if (tid < 128) {
        int rg = row0 + tid;
        float e = 0.f;
        if (rg < N_INST) {
            float a = rsum[tid] + bc[0];
            araw[rg] = a;
            u32 bits = __float_as_uint(a);
            u32 key = (bits & 0x80000000u) ? ~bits : (bits | 0x80000000u);
            uarr[rg] = key;
            atomicAdd(&hist[key >> 16], 1u);
            e = expf(a);
        }
        sW[tid] = e;
    }
    __syncthreads();
    if (tid < 128) {
        float e = sW[tid];
        for (int o = 32; o > 0; o >>= 1) e += __shfl_xor(e, o);
        if (lane == 0) atomicAdd(Zacc, e);
    }
    float accM = 0.f;
    for (int i = 0; i < 128; ++i)
        accM += sW[i] * b2f(h512[(size_t)(row0 + i) * D1 + tid]);
    atomicAdd(&Mpart[tid], accM);
}

// ---------------- topk collect with inline hist scan (every block computes boundaries)
__global__ void topk_collect(const u32* __restrict__ hist, const u32* __restrict__ uarr,
                             int* __restrict__ ctl, int* __restrict__ ids,
                             u32* __restrict__ cV0, int* __restrict__ cI0,
                             u32* __restrict__ cV1, int* __restrict__ cI1) {
    __shared__ int part[256];
    __shared__ int sp0, sb0, sp1, sb1;
    const int t = threadIdx.x;                 // 256
    const uint4* h4 = (const uint4*)hist;
    int s = 0;
    for (int j = 0; j < 64; ++j) {
        uint4 v = h4[t * 64 + j];
        s += (int)(v.x + v.y + v.z + v.w);
    }
    part[t] = s;
    __syncthreads();
    for (int off = 1; off < 256; off <<= 1) {
        int v = part[t];
        int a = (t >= off) ? part[t - off] : 0;
        __syncthreads();
        part[t] = v + a;
        __syncthreads();
    }
    int run = part[t] - s;
    for (int j = 0; j < 64; ++j) {
        uint4 v = h4[t * 64 + j];
        int c4[4]; c4[0] = (int)v.x; c4[1] = (int)v.y; c4[2] = (int)v.z; c4[3] = (int)v.w;
        #pragma unroll
        for (int e = 0; e < 4; ++e) {
            int cnt = c4[e];
            if (cnt > 0) {
                int b = t * 256 + j * 4 + e;
                int less = run, greater = N_INST - run - cnt;
                if (greater < TOPK && greater + cnt >= TOPK) { sp0 = b; sb0 = greater; }
                if (less < TOPK && less + cnt >= TOPK)       { sp1 = b; sb1 = less; }
            }
            run += cnt;
        }
    }
    __syncthreads();
    const int p0 = sp0, p1 = sp1;
    if (blockIdx.x == 0 && t == 0) { ctl[0] = sp0; ctl[1] = sb0; ctl[2] = sp1; ctl[3] = sb1; }

    int gt = blockIdx.x * blockDim.x + t;
    int nthr = gridDim.x * blockDim.x;
    for (int i = gt; i < N_INST; i += nthr) {
        u32 v = uarr[i];
        int b = (int)(v >> 16);
        if (b > p0)       { int p = atomicAdd(&ctl[8], 1);  ids[p] = i; }
        else if (b == p0) { int p = atomicAdd(&ctl[9], 1);  if (p < CAND_MAX) { cV0[p] = v; cI0[p] = i; } }
        if (b < p1)       { int p = atomicAdd(&ctl[10], 1); ids[TOPK + p] = i; }
        else if (b == p1) { int p = atomicAdd(&ctl[11], 1); if (p < CAND_MAX) { cV1[p] = v; cI1[p] = i; } }
    }
}

// ---------------- tail: topk finish + instance CE loss + final head (one block, 256 thr)
__global__ void tail_fused(const int* __restrict__ ctl,
                           const u32* __restrict__ cV0, const int* __restrict__ cI0,
                           const u32* __restrict__ cV1, const int* __restrict__ cI1,
                           int* __restrict__ ids, const u16* __restrict__ h512,
                           const float* __restrict__ W_inst, const float* __restrict__ b_inst,
                           const int* __restrict__ label, const float* __restrict__ Mpart,
                           const float* __restrict__ Zacc, const float* __restrict__ tabular,
                           const float* __restrict__ W_img, const float* __restrict__ b_img,
                           const float* __restrict__ W_tab, const float* __restrict__ b_tab,
                           const float* __restrict__ W_cls, const float* __restrict__ b_cls,
                           float* __restrict__ d_out) {
    __shared__ int h8[256];
    __shared__ int eq[2048];
    __shared__ int s_d1, s_k1, s_d2, s_fill, s_eqc;
    __shared__ float lsum;
    __shared__ float sM[512];
    __shared__ float stab[TDIM];
    __shared__ float red0[256], red1[256];
    __shared__ float simg;
    const int tid = threadIdx.x;               // 256
    const int lane = tid & 63, wid = tid >> 6;

    for (int mode = 0; mode < 2; ++mode) {
        int basem = ctl[mode * 2 + 1];
        int need = TOPK - basem;
        int ccnt = ctl[9 + mode * 2];
        if (ccnt > CAND_MAX) ccnt = CAND_MAX;
        const u32* cV = mode ? cV1 : cV0;
        const int* cI = mode ? cI1 : cI0;
        int* dst = ids + mode * TOPK;
        h8[tid] = 0; __syncthreads();
        for (int i = tid; i < ccnt; i += 256) atomicAdd(&h8[(cV[i] >> 8) & 255u], 1);
        __syncthreads();
        if (tid == 0) {
            int acc = 0, d, k = need;
            if (mode == 0) { for (d = 255; d >= 0; --d) { acc += h8[d]; if (acc >= k) break; } }
            else           { for (d = 0; d < 256; ++d)  { acc += h8[d]; if (acc >= k) break; } }
            s_d1 = d; s_k1 = k - (acc - h8[d]);
        }
        __syncthreads();
        int d1 = s_d1, k1 = s_k1;
        h8[tid] = 0; __syncthreads();
        for (int i = tid; i < ccnt; i += 256) {
            u32 v = cV[i];
            if (((v >> 8) & 255u) == (u32)d1) atomicAdd(&h8[v & 255u], 1);
        }
        __syncthreads();
        if (tid == 0) {
            int acc = 0, d, k = k1;
            if (mode == 0) { for (d = 255; d >= 0; --d) { acc += h8[d]; if (acc >= k) break; } }
            else           { for (d = 0; d < 256; ++d)  { acc += h8[d]; if (acc >= k) break; } }
            s_d2 = d; s_fill = 0; s_eqc = 0;
        }
        __syncthreads();
        u32 vth = ((u32)ctl[mode * 2] << 16) | ((u32)d1 << 8) | (u32)s_d2;
        for (int i = tid; i < ccnt; i += 256) {
            u32 v = cV[i];
            bool better = mode == 0 ? (v > vth) : (v < vth);
            if (better)        { int p = atomicAdd(&s_fill, 1); dst[basem + p] = cI[i]; }
            else if (v == vth) { int p = atomicAdd(&s_eqc, 1);  if (p < 2048) eq[p] = cI[i]; }
        }
        __syncthreads();
        if (tid == 0) {
            int have = basem + s_fill;
            int rem = TOPK - have;
            int m = s_eqc < 2048 ? s_eqc : 2048;
            int last = -1;
            for (int q = 0; q < rem; ++q) {
                int best = 0x7FFFFFFF;
                for (int s = 0; s < m; ++s) { int ix = eq[s]; if (ix > last && ix < best) best = ix; }
                dst[have + q] = best; last = best;
            }
        }
        __syncthreads();
    }

    if (tid == 0) lsum = 0.f;
    __syncthreads();
    const int lab = label[0];
    const float* W = W_inst + (size_t)lab * (D1 * 2);
    const float b0 = b_inst[lab * 2 + 0], b1 = b_inst[lab * 2 + 1];
    for (int i = 0; i < 32; ++i) {
        int r = wid * 32 + i;
        int row = ids[r];
        float s0 = 0.f, s1 = 0.f;
        for (int s = 0; s < 8; ++s) {
            int j = lane + 64 * s;
            float hv = b2f(h512[(size_t)row * D1 + j]);
            s0 += hv * W[j * 2 + 0];
            s1 += hv * W[j * 2 + 1];
        }
        for (int o = 32; o > 0; o >>= 1) { s0 += __shfl_xor(s0, o); s1 += __shfl_xor(s1, o); }
        if (lane == 0) {
            float l0 = s0 + b0, l1 = s1 + b1;
            float mx = fmaxf(l0, l1);
            float lse = mx + logf(expf(l0 - mx) + expf(l1 - mx));
            float lt = (r < TOPK) ? l1 : l0;
            atomicAdd(&lsum, lse - lt);
        }
    }
    __syncthreads();
    if (tid == 0) d_out[50005] = lsum / 128.f;

    float invZ = 1.f / Zacc[0];
    sM[tid] = Mpart[tid] * invZ;
    sM[tid + 256] = Mpart[tid + 256] * invZ;
    red0[tid] = sM[tid] * W_img[tid] + sM[tid + 256] * W_img[tid + 256];
    __syncthreads();
    for (int o = 128; o > 0; o >>= 1) { if (tid < o) red0[tid] += red0[tid + o]; __syncthreads(); }
    if (tid == 0) simg = 1.f / (1.f + expf(-(red0[0] + b_img[0])));
    if (tid < TDIM) {
        float t = b_tab[tid];
        for (int kx = 0; kx < TDIM; ++kx) t += tabular[kx] * W_tab[kx * TDIM + tid];
        stab[tid] = t;
    }
    __syncthreads();
    if (tid == 0) {
        float mx = stab[0];
        for (int o = 1; o < TDIM; ++o) mx = fmaxf(mx, stab[o]);
        float ss = 0.f;
        for (int o = 0; o < TDIM; ++o) { float e = expf(stab[o] - mx); stab[o] = e; ss += e; }
        for (int o = 0; o < TDIM; ++o) stab[o] = (stab[o] / ss) * tabular[o];
    }
    __syncthreads();
    float img = simg;
    float a0 = 0.f, a1 = 0.f;
    for (int j = tid; j < D1 + TDIM; j += 256) {
        float w = (j < D1) ? img * sM[j] : stab[j - D1];
        a0 += w * W_cls[j * 2 + 0];
        a1 += w * W_cls[j * 2 + 1];
    }
    red0[tid] = a0; red1[tid] = a1;
    __syncthreads();
    for (int o = 128; o > 0; o >>= 1) {
        if (tid < o) { red0[tid] += red0[tid + o]; red1[tid] += red1[tid + o]; }
        __syncthreads();
    }
    if (tid == 0) {
        float l0 = red0[0] + b_cls[0];
        float l1 = red1[0] + b_cls[1];
        d_out[0] = l0; d_out[1] = l1;
        float mx = fmaxf(l0, l1);
        float e0 = expf(l0 - mx), e1 = expf(l1 - mx);
        d_out[2] = e0 / (e0 + e1);
        d_out[3] = e1 / (e0 + e1);
        d_out[4] = (l1 > l0) ? 1.f : 0.f;
    }
}

extern "C" void kernel_launch(void* const* d_in, const int* in_sizes, int n_in,
                              void* d_out, int out_size, void* d_ws, size_t ws_size,
                              hipStream_t stream) {
    const float* h       = (const float*)d_in[0];
    const float* tabular = (const float*)d_in[1];
    const int*   label   = (const int*)d_in[2];
    const float* W_fc    = (const float*)d_in[3];
    const float* b_fc    = (const float*)d_in[4];
    const float* Wa      = (const float*)d_in[5];
    const float* ba      = (const float*)d_in[6];
    const float* Wb      = (const float*)d_in[7];
    const float* bb      = (const float*)d_in[8];
    const float* Wc      = (const float*)d_in[9];
    const float* bc      = (const float*)d_in[10];
    const float* W_inst  = (const float*)d_in[11];
    const float* b_inst  = (const float*)d_in[12];
    const float* W_img   = (const float*)d_in[13];
    const float* b_img   = (const float*)d_in[14];
    const float* W_tab   = (const float*)d_in[15];
    const float* b_tab   = (const float*)d_in[16];
    const float* W_cls   = (const float*)d_in[17];
    const float* b_cls   = (const float*)d_in[18];
    float* out = (float*)d_out;

    // workspace layout (~53 MB)
    u16* h512 = (u16*)d_ws;                          // NPAD x 512 bf16      (51.2 MB)
    u16* WfcT = h512 + (size_t)NPAD * D1;            // 512 x 1024 bf16      (1 MB)
    u16* WaT  = WfcT + (size_t)D1 * LIN;             // 256 x 512 bf16
    u16* WbT  = WaT + (size_t)D2 * D1;
    u32* uarr = (u32*)(WbT + (size_t)D2 * D1);       // NPAD sortable keys
    float* accum = (float*)(uarr + NPAD);            // [0]=Z, [8..520)=Mpart
    float* Zacc  = accum;
    float* Mpart = accum + 8;
    int* ids = (int*)(accum + 8 + D1);               // 128 selected indices
    int* ctl = ids + 128;                            // 16 ints: buckets+counters
    u32* hist = (u32*)(ctl + 16);                    // 65536 bins
    u32* cV0 = hist + NBIN;
    int* cI0 = (int*)(cV0 + CAND_MAX);
    u32* cV1 = (u32*)(cI0 + CAND_MAX);
    int* cI1 = (int*)(cV1 + CAND_MAX);

    pack_w<<<dim3(256), dim3(256), 0, stream>>>(W_fc, Wa, Wb, WfcT, WaT, WbT, (u32*)accum);
    gemm_fc<<<dim3(2, NPAD / 128), dim3(512), 0, stream>>>(h, WfcT, b_fc, h512);
    gemm_attn<<<dim3(NPAD / 128), dim3(512), 0, stream>>>(
        h512, WaT, WbT, ba, bb, Wc, bc, out + 5, uarr, hist, Zacc, Mpart);
    topk_collect<<<dim3(128), dim3(256), 0, stream>>>(hist, uarr, ctl, ids, cV0, cI0, cV1, cI1);
    tail_fused<<<dim3(1), dim3(256), 0, stream>>>(
        ctl, cV0, cI0, cV1, cI1, ids, h512, W_inst, b_inst, label,
        Mpart, Zacc, tabular, W_img, b_img, W_tab, b_tab, W_cls, b_cls, out);
}

// Round 13
// 281.799 us; speedup vs baseline: 1.3654x; 1.0557x over previous
//
#include <hip/hip_runtime.h>
#include <stdint.h>

typedef __bf16 bf16x8 __attribute__((ext_vector_type(8)));
typedef float f32x4 __attribute__((ext_vector_type(4)));
typedef unsigned short u16;
typedef unsigned int u32;

#define N_INST 50000
#define NPAD   50048   // 391 * 128
#define LIN    1024
#define D1     512
#define D2     256
#define TOPK   64
#define TDIM   49
#define NBIN   65536
#define CAND_MAX 8192
// dwords to zero: accum(520) + ids(128) + ctl(16) + hist(65536)
#define ZERO_DW (520 + 128 + 16 + NBIN)

__device__ __forceinline__ float b2f(u16 u) {
    union { float f; u32 i; } x; x.i = ((u32)u) << 16; return x.f;
}
__device__ __forceinline__ u16 f2b(float f) {
    union { float f; u32 i; } x; x.f = f;
    u32 r = x.i + 0x7FFFu + ((x.i >> 16) & 1u);   // RNE
    return (u16)(r >> 16);
}
// async global->LDS, 16B per lane. dst must be linear in lane order (wave-uniform base + lane*16).
__device__ __forceinline__ void gload16(const void* g, void* l) {
    __builtin_amdgcn_global_load_lds((const __attribute__((address_space(1))) void*)g,
                                     (__attribute__((address_space(3))) void*)l, 16, 0, 0);
}
// byte offset of a swizzled [row][64 bf16] tile element (T2 st-style XOR swizzle)
__device__ __forceinline__ u32 swz(int row, int bytecol) {
    return (u32)(row * 128 + (bytecol ^ ((row & 7) << 4)));
}

// ---------------- pack weights (tiny): W_fc -> WfcT bf16 [512][1024]; Wa/Wb -> [256][512]
// Also zeroes the accumulator/histogram region.
__global__ void pack_w(const float* __restrict__ W_fc, const float* __restrict__ Wa,
                       const float* __restrict__ Wb, u16* __restrict__ WfcT,
                       u16* __restrict__ WaT, u16* __restrict__ WbT, u32* __restrict__ zbase) {
    int gt = blockIdx.x * blockDim.x + threadIdx.x;
    int nthr = gridDim.x * blockDim.x;
    for (int z = gt; z < ZERO_DW; z += nthr) zbase[z] = 0u;
    for (int e = gt; e < D1 * LIN; e += nthr) {
        int n = e >> 10, k = e & 1023;
        WfcT[e] = f2b(W_fc[(size_t)k * D1 + n]);
    }
    for (int f = gt; f < D2 * D1; f += nthr) {
        int j = f >> 9, k = f & 511;
        WaT[f] = f2b(Wa[(size_t)k * D2 + j]);
        WbT[f] = f2b(Wb[(size_t)k * D2 + j]);
    }
}

// ---------------- GEMM1: h512 = relu(h_fp32 @ W_fc + b_fc). R6 2-barrier structure at
// 2 blocks/CU: __launch_bounds__(512,4) = 4 waves/EU = 2 co-resident 512-thread blocks
// (LDS 48 KB x2 = 96 <= 160; VGPR cap 128 >= 72 measured — no spill, R9 lesson checked).
// When one block stalls in its barrier drain, the other block's waves feed the pipes (m114).
// BM=128, BN=256, BK=64, 8 waves 2x4. A: fp32 reg-prefetch -> bf16 -> swizzled ds_write.
// B: global_load_lds w/ pre-swizzled source. All LDS reads XOR-swizzled (T2).
__global__ __launch_bounds__(512, 4)
void gemm_fc(const float* __restrict__ h, const u16* __restrict__ WfcT,
             const float* __restrict__ b_fc, u16* __restrict__ h512) {
    __shared__ __align__(16) u16 lA[128 * 64];    // 16 KB
    __shared__ __align__(16) u16 lB[256 * 64];    // 32 KB
    const int tid = threadIdx.x;
    const int lane = tid & 63, wid = tid >> 6;
    const int wr = wid >> 2, wc = wid & 3;        // 2 x 4 wave grid, 64x64 each
    const int lanelo = lane & 15, lanehi = lane >> 4;
    const int row0 = blockIdx.y * 128;
    const int col0 = blockIdx.x * 256;

    const int arow = tid >> 2;                    // 0..127
    const int aseg = tid & 3;                     // 16 floats each
    int srow = row0 + arow; if (srow >= N_INST) srow = N_INST - 1;
    const float* abase = h + (size_t)srow * LIN + aseg * 16;
    u16* aw0 = (u16*)((char*)lA + swz(arow, aseg * 32));
    u16* aw1 = (u16*)((char*)lA + swz(arow, aseg * 32 + 16));

    f32x4 acc[4][4];
    const f32x4 z4 = {0.f, 0.f, 0.f, 0.f};
    #pragma unroll
    for (int m = 0; m < 4; ++m)
        #pragma unroll
        for (int n = 0; n < 4; ++n) acc[m][n] = z4;

    float4 a0, a1, a2, a3;
    { const float4* ap = (const float4*)abase; a0 = ap[0]; a1 = ap[1]; a2 = ap[2]; a3 = ap[3]; }

    for (int kt = 0; kt < LIN / 64; ++kt) {
        // B: 256x64 bf16 = 2048 chunks, async direct-to-LDS, source pre-swizzled
        #pragma unroll
        for (int q = 0; q < 4; ++q) {
            int c = tid + 512 * q;
            int col = c >> 3, d8 = c & 7;
            int k8 = d8 ^ (col & 7);
            gload16(WfcT + (size_t)(col0 + col) * LIN + kt * 64 + k8 * 8, (char*)lB + c * 16);
        }
        // A: convert prefetched fp32 regs -> bf16, swizzled ds_write
        {
            bf16x8 w0, w1;
            w0[0] = (__bf16)a0.x; w0[1] = (__bf16)a0.y; w0[2] = (__bf16)a0.z; w0[3] = (__bf16)a0.w;
            w0[4] = (__bf16)a1.x; w0[5] = (__bf16)a1.y; w0[6] = (__bf16)a1.z; w0[7] = (__bf16)a1.w;
            w1[0] = (__bf16)a2.x; w1[1] = (__bf16)a2.y; w1[2] = (__bf16)a2.z; w1[3] = (__bf16)a2.w;
            w1[4] = (__bf16)a3.x; w1[5] = (__bf16)a3.y; w1[6] = (__bf16)a3.z; w1[7] = (__bf16)a3.w;
            *(bf16x8*)aw0 = w0;
            *(bf16x8*)aw1 = w1;
        }
        __syncthreads();
        // prefetch next A tile (latency hides under MFMA below; drained at next barrier)
        if (kt + 1 < LIN / 64) {
            const float4* ap = (const float4*)(abase + (kt + 1) * 64);
            a0 = ap[0]; a1 = ap[1]; a2 = ap[2]; a3 = ap[3];
        }
        #pragma unroll
        for (int kk = 0; kk < 2; ++kk) {
            bf16x8 af[4], bfr[4];
            #pragma unroll
            for (int m = 0; m < 4; ++m) {
                int row = wr * 64 + m * 16 + lanelo;
                af[m] = *(const bf16x8*)((char*)lA + swz(row, kk * 64 + lanehi * 16));
            }
            #pragma unroll
            for (int n = 0; n < 4; ++n) {
                int col = wc * 64 + n * 16 + lanelo;
                bfr[n] = *(const bf16x8*)((char*)lB + swz(col, kk * 64 + lanehi * 16));
            }
            #pragma unroll
            for (int m = 0; m < 4; ++m)
                #pragma unroll
                for (int n = 0; n < 4; ++n)
                    acc[m][n] = __builtin_amdgcn_mfma_f32_16x16x32_bf16(af[m], bfr[n], acc[m][n], 0, 0, 0);
        }
        __syncthreads();
    }
    // epilogue: bias + relu -> bf16
    #pragma unroll
    for (int n = 0; n < 4; ++n) {
        int col = col0 + wc * 64 + n * 16 + lanelo;
        float bias = b_fc[col];
        #pragma unroll
        for (int m = 0; m < 4; ++m) {
            int rbase = row0 + wr * 64 + m * 16 + 4 * lanehi;
            #pragma unroll
            for (int r = 0; r < 4; ++r) {
                float v = acc[m][n][r] + bias;
                v = v > 0.f ? v : 0.f;
                h512[(size_t)(rbase + r) * D1 + col] = f2b(v);
            }
        }
    }
}

// ---------------- GEMM2 fused + sortable keys + 64K-bin key histogram + Z/M partials
// (exact R6 version — keeps (512,2): acc uses 128 VGPRs, a 128-cap would spill)
__global__ __launch_bounds__(512, 2)
void gemm_attn(const u16* __restrict__ h512, const u16* __restrict__ WaT,
               const u16* __restrict__ WbT, const float* __restrict__ ba,
               const float* __restrict__ bb, const float* __restrict__ Wc,
               const float* __restrict__ bc, float* __restrict__ araw,
               u32* __restrict__ uarr, u32* __restrict__ hist,
               float* __restrict__ Zacc, float* __restrict__ Mpart) {
    __shared__ __align__(16) u16 lA[128 * 64];
    __shared__ __align__(16) u16 lBa[256 * 64];
    __shared__ __align__(16) u16 lBb[256 * 64];
    __shared__ float rsum[128];
    __shared__ float sW[128];
    const int tid = threadIdx.x;
    const int lane = tid & 63, wid = tid >> 6;
    const int wr = wid >> 2, wc4 = wid & 3;
    const int lanelo = lane & 15, lanehi = lane >> 4;
    const int row0 = blockIdx.x * 128;

    f32x4 accA[4][4], accB[4][4];
    const f32x4 z4 = {0.f, 0.f, 0.f, 0.f};
    for (int m = 0; m < 4; ++m)
        for (int n = 0; n < 4; ++n) { accA[m][n] = z4; accB[m][n] = z4; }

    for (int kt = 0; kt < D1 / 64; ++kt) {
        #pragma unroll
        for (int q = 0; q < 2; ++q) {
            int c = tid + 512 * q;
            int row = c >> 3, d8 = c & 7;
            int k8 = d8 ^ (row & 7);
            gload16(h512 + (size_t)(row0 + row) * D1 + kt * 64 + k8 * 8, (char*)lA + c * 16);
        }
        #pragma unroll
        for (int q = 0; q < 4; ++q) {
            int c = tid + 512 * q;
            int col = c >> 3, d8 = c & 7;
            int k8 = d8 ^ (col & 7);
            gload16(WaT + (size_t)col * D1 + kt * 64 + k8 * 8, (char*)lBa + c * 16);
            gload16(WbT + (size_t)col * D1 + kt * 64 + k8 * 8, (char*)lBb + c * 16);
        }
        __syncthreads();
        #pragma unroll
        for (int kk = 0; kk < 2; ++kk) {
            bf16x8 af[4], ga[4], gb[4];
            #pragma unroll
            for (int m = 0; m < 4; ++m) {
                int row = wr * 64 + m * 16 + lanelo;
                af[m] = *(const bf16x8*)((char*)lA + swz(row, kk * 64 + lanehi * 16));
            }
            #pragma unroll
            for (int n = 0; n < 4; ++n) {
                int col = wc4 * 64 + n * 16 + lanelo;
                u32 off = swz(col, kk * 64 + lanehi * 16);
                ga[n] = *(const bf16x8*)((char*)lBa + off);
                gb[n] = *(const bf16x8*)((char*)lBb + off);
            }
            #pragma unroll
            for (int m = 0; m < 4; ++m)
                #pragma unroll
                for (int n = 0; n < 4; ++n) {
                    accA[m][n] = __builtin_amdgcn_mfma_f32_16x16x32_bf16(af[m], ga[n], accA[m][n], 0, 0, 0);
                    accB[m][n] = __builtin_amdgcn_mfma_f32_16x16x32_bf16(af[m], gb[n], accB[m][n], 0, 0, 0);
                }
        }
        __syncthreads();
    }

    if (tid < 128) rsum[tid] = 0.f;
    __syncthreads();

    float baR[4], bbR[4], wcR[4];
    #pragma unroll
    for (int n = 0; n < 4; ++n) {
        int j = wc4 * 64 + n * 16 + lanelo;
        baR[n] = ba[j]; bbR[n] = bb[j]; wcR[n] = Wc[j];
    }
    #pragma unroll
    for (int m = 0; m < 4; ++m) {
        #pragma unroll
        for (int r = 0; r < 4; ++r) {
            float s = 0.f;
            #pragma unroll
            for (int n = 0; n < 4; ++n) {
                float av = accA[m][n][r] + baR[n];
                float bv = accB[m][n][r] + bbR[n];
                float p = tanhf(av) / (1.f + expf(-bv));
                s += p * wcR[n];
            }
            s += __shfl_xor(s, 1); s += __shfl_xor(s, 2);
            s += __shfl_xor(s, 4); s += __shfl_xor(s, 8);
            if (lanelo == 0) atomicAdd(&rsum[wr * 64 + m * 16 + 4 * lanehi + r], s);
        }
    }
    __syncthreads();

    if (tid < 128) {
        int rg = row0 + tid;
        float e = 0.f;
        if (rg < N_INST) {
            float a = rsum[tid] + bc[0];
            araw[rg] = a;
            u32 bits = __float_as_uint(a);
            u32 key = (bits & 0x80000000u) ? ~bits : (bits | 0x80000000u);
            uarr[rg] = key;
            atomicAdd(&hist[key >> 16], 1u);
            e = expf(a);
        }
        sW[tid] = e;
    }
    __syncthreads();
    if (tid < 128) {
        float e = sW[tid];
        for (int o = 32; o > 0; o >>= 1) e += __shfl_xor(e, o);
        if (lane == 0) atomicAdd(Zacc, e);
    }
    float accM = 0.f;
    for (int i = 0; i < 128; ++i)
        accM += sW[i] * b2f(h512[(size_t)(row0 + i) * D1 + tid]);
    atomicAdd(&Mpart[tid], accM);
}

// ---------------- topk collect with inline hist scan (every block computes boundaries)
__global__ void topk_collect(const u32* __restrict__ hist, const u32* __restrict__ uarr,
                             int* __restrict__ ctl, int* __restrict__ ids,
                             u32* __restrict__ cV0, int* __restrict__ cI0,
                             u32* __restrict__ cV1, int* __restrict__ cI1) {
    __shared__ int part[256];
    __shared__ int sp0, sb0, sp1, sb1;
    const int t = threadIdx.x;                 // 256
    const uint4* h4 = (const uint4*)hist;
    int s = 0;
    for (int j = 0; j < 64; ++j) {
        uint4 v = h4[t * 64 + j];
        s += (int)(v.x + v.y + v.z + v.w);
    }
    part[t] = s;
    __syncthreads();
    for (int off = 1; off < 256; off <<= 1) {
        int v = part[t];
        int a = (t >= off) ? part[t - off] : 0;
        __syncthreads();
        part[t] = v + a;
        __syncthreads();
    }
    int run = part[t] - s;
    for (int j = 0; j < 64; ++j) {
        uint4 v = h4[t * 64 + j];
        int c4[4]; c4[0] = (int)v.x; c4[1] = (int)v.y; c4[2] = (int)v.z; c4[3] = (int)v.w;
        #pragma unroll
        for (int e = 0; e < 4; ++e) {
            int cnt = c4[e];
            if (cnt > 0) {
                int b = t * 256 + j * 4 + e;
                int less = run, greater = N_INST - run - cnt;
                if (greater < TOPK && greater + cnt >= TOPK) { sp0 = b; sb0 = greater; }
                if (less < TOPK && less + cnt >= TOPK)       { sp1 = b; sb1 = less; }
            }
            run += cnt;
        }
    }
    __syncthreads();
    const int p0 = sp0, p1 = sp1;
    if (blockIdx.x == 0 && t == 0) { ctl[0] = sp0; ctl[1] = sb0; ctl[2] = sp1; ctl[3] = sb1; }

    int gt = blockIdx.x * blockDim.x + t;
    int nthr = gridDim.x * blockDim.x;
    for (int i = gt; i < N_INST; i += nthr) {
        u32 v = uarr[i];
        int b = (int)(v >> 16);
        if (b > p0)       { int p = atomicAdd(&ctl[8], 1);  ids[p] = i; }
        else if (b == p0) { int p = atomicAdd(&ctl[9], 1);  if (p < CAND_MAX) { cV0[p] = v; cI0[p] = i; } }
        if (b < p1)       { int p = atomicAdd(&ctl[10], 1); ids[TOPK + p] = i; }
        else if (b == p1) { int p = atomicAdd(&ctl[11], 1); if (p < CAND_MAX) { cV1[p] = v; cI1[p] = i; } }
    }
}

// ---------------- tail: topk finish + instance CE loss + final head (one block, 256 thr)
__global__ void tail_fused(const int* __restrict__ ctl,
                           const u32* __restrict__ cV0, const int* __restrict__ cI0,
                           const u32* __restrict__ cV1, const int* __restrict__ cI1,
                           int* __restrict__ ids, const u16* __restrict__ h512,
                           const float* __restrict__ W_inst, const float* __restrict__ b_inst,
                           const int* __restrict__ label, const float* __restrict__ Mpart,
                           const float* __restrict__ Zacc, const float* __restrict__ tabular,
                           const float* __restrict__ W_img, const float* __restrict__ b_img,
                           const float* __restrict__ W_tab, const float* __restrict__ b_tab,
                           const float* __restrict__ W_cls, const float* __restrict__ b_cls,
                           float* __restrict__ d_out) {
    __shared__ int h8[256];
    __shared__ int eq[2048];
    __shared__ int s_d1, s_k1, s_d2, s_fill, s_eqc;
    __shared__ float lsum;
    __shared__ float sM[512];
    __shared__ float stab[TDIM];
    __shared__ float red0[256], red1[256];
    __shared__ float simg;
    const int tid = threadIdx.x;               // 256
    const int lane = tid & 63, wid = tid >> 6;

    for (int mode = 0; mode < 2; ++mode) {
        int basem = ctl[mode * 2 + 1];
        int need = TOPK - basem;
        int ccnt = ctl[9 + mode * 2];
        if (ccnt > CAND_MAX) ccnt = CAND_MAX;
        const u32* cV = mode ? cV1 : cV0;
        const int* cI = mode ? cI1 : cI0;
        int* dst = ids + mode * TOPK;
        h8[tid] = 0; __syncthreads();
        for (int i = tid; i < ccnt; i += 256) atomicAdd(&h8[(cV[i] >> 8) & 255u], 1);
        __syncthreads();
        if (tid == 0) {
            int acc = 0, d, k = need;
            if (mode == 0) { for (d = 255; d >= 0; --d) { acc += h8[d]; if (acc >= k) break; } }
            else           { for (d = 0; d < 256; ++d)  { acc += h8[d]; if (acc >= k) break; } }
            s_d1 = d; s_k1 = k - (acc - h8[d]);
        }
        __syncthreads();
        int d1 = s_d1, k1 = s_k1;
        h8[tid] = 0; __syncthreads();
        for (int i = tid; i < ccnt; i += 256) {
            u32 v = cV[i];
            if (((v >> 8) & 255u) == (u32)d1) atomicAdd(&h8[v & 255u], 1);
        }
        __syncthreads();
        if (tid == 0) {
            int acc = 0, d, k = k1;
            if (mode == 0) { for (d = 255; d >= 0; --d) { acc += h8[d]; if (acc >= k) break; } }
            else           { for (d = 0; d < 256; ++d)  { acc += h8[d]; if (acc >= k) break; } }
            s_d2 = d; s_fill = 0; s_eqc = 0;
        }
        __syncthreads();
        u32 vth = ((u32)ctl[mode * 2] << 16) | ((u32)d1 << 8) | (u32)s_d2;
        for (int i = tid; i < ccnt; i += 256) {
            u32 v = cV[i];
            bool better = mode == 0 ? (v > vth) : (v < vth);
            if (better)        { int p = atomicAdd(&s_fill, 1); dst[basem + p] = cI[i]; }
            else if (v == vth) { int p = atomicAdd(&s_eqc, 1);  if (p < 2048) eq[p] = cI[i]; }
        }
        __syncthreads();
        if (tid == 0) {
            int have = basem + s_fill;
            int rem = TOPK - have;
            int m = s_eqc < 2048 ? s_eqc : 2048;
            int last = -1;
            for (int q = 0; q < rem; ++q) {
                int best = 0x7FFFFFFF;
                for (int s = 0; s < m; ++s) { int ix = eq[s]; if (ix > last && ix < best) best = ix; }
                dst[have + q] = best; last = best;
            }
        }
        __syncthreads();
    }

    if (tid == 0) lsum = 0.f;
    __syncthreads();
    const int lab = label[0];
    const float* W = W_inst + (size_t)lab * (D1 * 2);
    const float b0 = b_inst[lab * 2 + 0], b1 = b_inst[lab * 2 + 1];
    for (int i = 0; i < 32; ++i) {
        int r = wid * 32 + i;
        int row = ids[r];
        float s0 = 0.f, s1 = 0.f;
        for (int s = 0; s < 8; ++s) {
            int j = lane + 64 * s;
            float hv = b2f(h512[(size_t)row * D1 + j]);
            s0 += hv * W[j * 2 + 0];
            s1 += hv * W[j * 2 + 1];
        }
        for (int o = 32; o > 0; o >>= 1) { s0 += __shfl_xor(s0, o); s1 += __shfl_xor(s1, o); }
        if (lane == 0) {
            float l0 = s0 + b0, l1 = s1 + b1;
            float mx = fmaxf(l0, l1);
            float lse = mx + logf(expf(l0 - mx) + expf(l1 - mx));
            float lt = (r < TOPK) ? l1 : l0;
            atomicAdd(&lsum, lse - lt);
        }
    }
    __syncthreads();
    if (tid == 0) d_out[50005] = lsum / 128.f;

    float invZ = 1.f / Zacc[0];
    sM[tid] = Mpart[tid] * invZ;
    sM[tid + 256] = Mpart[tid + 256] * invZ;
    red0[tid] = sM[tid] * W_img[tid] + sM[tid + 256] * W_img[tid + 256];
    __syncthreads();
    for (int o = 128; o > 0; o >>= 1) { if (tid < o) red0[tid] += red0[tid + o]; __syncthreads(); }
    if (tid == 0) simg = 1.f / (1.f + expf(-(red0[0] + b_img[0])));
    if (tid < TDIM) {
        float t = b_tab[tid];
        for (int kx = 0; kx < TDIM; ++kx) t += tabular[kx] * W_tab[kx * TDIM + tid];
        stab[tid] = t;
    }
    __syncthreads();
    if (tid == 0) {
        float mx = stab[0];
        for (int o = 1; o < TDIM; ++o) mx = fmaxf(mx, stab[o]);
        float ss = 0.f;
        for (int o = 0; o < TDIM; ++o) { float e = expf(stab[o] - mx); stab[o] = e; ss += e; }
        for (int o = 0; o < TDIM; ++o) stab[o] = (stab[o] / ss) * tabular[o];
    }
    __syncthreads();
    float img = simg;
    float a0 = 0.f, a1 = 0.f;
    for (int j = tid; j < D1 + TDIM; j += 256) {
        float w = (j < D1) ? img * sM[j] : stab[j - D1];
        a0 += w * W_cls[j * 2 + 0];
        a1 += w * W_cls[j * 2 + 1];
    }
    red0[tid] = a0; red1[tid] = a1;
    __syncthreads();
    for (int o = 128; o > 0; o >>= 1) {
        if (tid < o) { red0[tid] += red0[tid + o]; red1[tid] += red1[tid + o]; }
        __syncthreads();
    }
    if (tid == 0) {
        float l0 = red0[0] + b_cls[0];
        float l1 = red1[0] + b_cls[1];
        d_out[0] = l0; d_out[1] = l1;
        float mx = fmaxf(l0, l1);
        float e0 = expf(l0 - mx), e1 = expf(l1 - mx);
        d_out[2] = e0 / (e0 + e1);
        d_out[3] = e1 / (e0 + e1);
        d_out[4] = (l1 > l0) ? 1.f : 0.f;
    }
}

extern "C" void kernel_launch(void* const* d_in, const int* in_sizes, int n_in,
                              void* d_out, int out_size, void* d_ws, size_t ws_size,
                              hipStream_t stream) {
    const float* h       = (const float*)d_in[0];
    const float* tabular = (const float*)d_in[1];
    const int*   label   = (const int*)d_in[2];
    const float* W_fc    = (const float*)d_in[3];
    const float* b_fc    = (const float*)d_in[4];
    const float* Wa      = (const float*)d_in[5];
    const float* ba      = (const float*)d_in[6];
    const float* Wb      = (const float*)d_in[7];
    const float* bb      = (const float*)d_in[8];
    const float* Wc      = (const float*)d_in[9];
    const float* bc      = (const float*)d_in[10];
    const float* W_inst  = (const float*)d_in[11];
    const float* b_inst  = (const float*)d_in[12];
    const float* W_img   = (const float*)d_in[13];
    const float* b_img   = (const float*)d_in[14];
    const float* W_tab   = (const float*)d_in[15];
    const float* b_tab   = (const float*)d_in[16];
    const float* W_cls   = (const float*)d_in[17];
    const float* b_cls   = (const float*)d_in[18];
    float* out = (float*)d_out;

    // workspace layout (~53 MB)
    u16* h512 = (u16*)d_ws;                          // NPAD x 512 bf16      (51.2 MB)
    u16* WfcT = h512 + (size_t)NPAD * D1;            // 512 x 1024 bf16      (1 MB)
    u16* WaT  = WfcT + (size_t)D1 * LIN;             // 256 x 512 bf16
    u16* WbT  = WaT + (size_t)D2 * D1;
    u32* uarr = (u32*)(WbT + (size_t)D2 * D1);       // NPAD sortable keys
    float* accum = (float*)(uarr + NPAD);            // [0]=Z, [8..520)=Mpart
    float* Zacc  = accum;
    float* Mpart = accum + 8;
    int* ids = (int*)(accum + 8 + D1);               // 128 selected indices
    int* ctl = ids + 128;                            // 16 ints: buckets+counters
    u32* hist = (u32*)(ctl + 16);                    // 65536 bins
    u32* cV0 = hist + NBIN;
    int* cI0 = (int*)(cV0 + CAND_MAX);
    u32* cV1 = (u32*)(cI0 + CAND_MAX);
    int* cI1 = (int*)(cV1 + CAND_MAX);

    pack_w<<<dim3(256), dim3(256), 0, stream>>>(W_fc, Wa, Wb, WfcT, WaT, WbT, (u32*)accum);
    gemm_fc<<<dim3(2, NPAD / 128), dim3(512), 0, stream>>>(h, WfcT, b_fc, h512);
    gemm_attn<<<dim3(NPAD / 128), dim3(512), 0, stream>>>(
        h512, WaT, WbT, ba, bb, Wc, bc, out + 5, uarr, hist, Zacc, Mpart);
    topk_collect<<<dim3(128), dim3(256), 0, stream>>>(hist, uarr, ctl, ids, cV0, cI0, cV1, cI1);
    tail_fused<<<dim3(1), dim3(256), 0, stream>>>(
        ctl, cV0, cI0, cV1, cI1, ids, h512, W_inst, b_inst, label,
        Mpart, Zacc, tabular, W_img, b_img, W_tab, b_tab, W_cls, b_cls, out);
}